// Round 9
// baseline (444.688 us; speedup 1.0000x reference)
//
#include <hip/hip_runtime.h>
#include <hip/hip_bf16.h>
#include <math.h>

#define NN 50000
#define NPAD 50048            // 1564 chunks of 32 rows
#define NE 800000
#define DD 128
#define NCLS 10
#define SCAN_BLOCK 1024
#define NTILES ((NN + 1 + SCAN_BLOCK - 1) / SCAN_BLOCK)  // 49

typedef short s16x8 __attribute__((ext_vector_type(8)));
typedef float f32x4 __attribute__((ext_vector_type(4)));

__device__ __forceinline__ unsigned short f2bf(float x) {
  __hip_bfloat16 h = __float2bfloat16(x);
  return __builtin_bit_cast(unsigned short, h);
}

// ---- custom fp8: s|eeee|mmm, bias 7, no denormals (flush |v|<2^-6), sat 480.
// decode = as_float(((c&0x80)<<24)|((c&0x7F)<<20)) * 2^120  (scale folded into w).
__device__ __forceinline__ unsigned int f2fp8(float x) {
  unsigned int b = __float_as_uint(x);
  unsigned int s = (b >> 24) & 0x80u;
  int e = (int)((b >> 23) & 255u) - 120;   // target exp field
  unsigned int m23 = b & 0x7FFFFFu;
  if (e >= 16) return s | 0x7F;            // saturate to 480
  if (e <= 0) return s;                    // flush to zero
  unsigned int m = m23 >> 20;              // 3 mantissa bits
  unsigned int rem = m23 & 0xFFFFFu;
  if (rem > 0x80000u || (rem == 0x80000u && (m & 1u))) {
    ++m;
    if (m == 8u) { m = 0; ++e; if (e >= 16) return s | 0x7F; }
  }
  return s | ((unsigned int)e << 3) | m;
}

// ---- monotonic float<->uint key for atomic max over floats ----
__device__ __forceinline__ unsigned int fkey(float f) {
  unsigned int u = __float_as_uint(f);
  return u ^ ((u & 0x80000000u) ? 0xFFFFFFFFu : 0x80000000u);
}
__device__ __forceinline__ float funkey(unsigned int k) {
  unsigned int u = (k & 0x80000000u) ? (k ^ 0x80000000u) : ~k;
  return __uint_as_float(u);
}

// ---- CSR build ----
__global__ void k_count(const int* __restrict__ edst, int* __restrict__ offs) {
  int e = blockIdx.x * blockDim.x + threadIdx.x;
  if (e < NE) atomicAdd(&offs[edst[e] + 1], 1);
}

__global__ void k_scan_partial(const int* __restrict__ offs, int* __restrict__ bsum) {
  __shared__ int red[SCAN_BLOCK];
  int i = blockIdx.x * SCAN_BLOCK + threadIdx.x;
  red[threadIdx.x] = (i < NN + 1) ? offs[i] : 0;
  __syncthreads();
  for (int off = SCAN_BLOCK / 2; off > 0; off >>= 1) {
    if ((int)threadIdx.x < off) red[threadIdx.x] += red[threadIdx.x + off];
    __syncthreads();
  }
  if (threadIdx.x == 0) bsum[blockIdx.x] = red[0];
}

__global__ void k_scan_bsum(int* __restrict__ bsum) {
  if (threadIdx.x == 0) {
    int run = 0;
    for (int i = 0; i < NTILES; ++i) { int v = bsum[i]; bsum[i] = run; run += v; }
  }
}

__global__ void k_scan_final(int* __restrict__ offs, const int* __restrict__ bsum,
                             int* __restrict__ cursor) {
  __shared__ int tmp[SCAN_BLOCK];
  int i = blockIdx.x * SCAN_BLOCK + threadIdx.x;
  int v = (i < NN + 1) ? offs[i] : 0;
  tmp[threadIdx.x] = v;
  __syncthreads();
  for (int off = 1; off < SCAN_BLOCK; off <<= 1) {
    int t = ((int)threadIdx.x >= off) ? tmp[threadIdx.x - off] : 0;
    __syncthreads();
    tmp[threadIdx.x] += t;
    __syncthreads();
  }
  int incl = tmp[threadIdx.x] + bsum[blockIdx.x];
  if (i < NN + 1) {
    offs[i] = incl;
    if (i < NN) cursor[i] = incl;
  }
}

__global__ void k_fill(const int* __restrict__ esrc, const int* __restrict__ edst,
                       const float* __restrict__ ew, int* __restrict__ cursor,
                       int2* __restrict__ csr) {
  int e = blockIdx.x * blockDim.x + threadIdx.x;
  if (e < NE) {
    int d = edst[e];
    int p = atomicAdd(&cursor[d], 1);
    csr[p] = make_int2(esrc[e], __float_as_int(ew[e]));
  }
}

// ---- convert W1..3 -> transposed bf16 WT[c][k]; also zero omax ----
__global__ __launch_bounds__(256) void k_cvtW(const float* __restrict__ W1,
    const float* __restrict__ W2, const float* __restrict__ W3,
    unsigned short* __restrict__ WT1, unsigned short* __restrict__ WT2,
    unsigned short* __restrict__ WT3, unsigned int* __restrict__ omax) {
  int i = blockIdx.x * 256 + threadIdx.x;
  if (i < 3 * DD) omax[i] = 0u;
  if (i < DD * DD) {
    int k = i >> 7, c = i & 127;
    WT1[c * DD + k] = f2bf(W1[i]);
    WT2[c * DD + k] = f2bf(W2[i]);
    WT3[c * DD + k] = f2bf(W3[i]);
  }
}

// ---- MFMA GEMM, LDS-staged: S[r][c] = fp8(sum_k H[r][k] W[k][c]) ----
// block = 256 thr (4 waves), tile = 32 rows x 128 cols. grid = NPAD/32.
template <int F32IN>
__global__ __launch_bounds__(256) void k_mm(const void* __restrict__ Hv,
                                            const unsigned short* __restrict__ Wt,
                                            unsigned char* __restrict__ Sout) {
  __shared__ unsigned short Hl[32 * DD];   // 8 KB, byte-addressed below
  char* lb = (char*)Hl;
  const int wave = threadIdx.x >> 6, lane = threadIdx.x & 63;
  const int l15 = lane & 15, lk16 = (lane >> 4);   // lk = lk16*8 elems
  const int r0 = blockIdx.x * 32;

#pragma unroll
  for (int j = 0; j < 2; ++j) {
    const int idx = threadIdx.x + j * 256;     // 0..511 granules of 16B
    const int B = idx * 16;
    const int row = B >> 8;
    const int addr = B ^ ((row & 7) << 4);
    if (F32IN) {
      const float* H = (const float*)Hv;
      const int r = r0 + row;
      float4 a = make_float4(0.f, 0.f, 0.f, 0.f), b = a;
      if (r < NN) {
        const float* src = H + (size_t)r * DD + ((B & 255) >> 1);
        a = *(const float4*)src;
        b = *(const float4*)(src + 4);
      }
      uint4 pv;
      pv.x = (uint)f2bf(a.x) | ((uint)f2bf(a.y) << 16);
      pv.y = (uint)f2bf(a.z) | ((uint)f2bf(a.w) << 16);
      pv.z = (uint)f2bf(b.x) | ((uint)f2bf(b.y) << 16);
      pv.w = (uint)f2bf(b.z) | ((uint)f2bf(b.w) << 16);
      *(uint4*)(lb + addr) = pv;
    } else {
      const char* H = (const char*)Hv;
      uint4 v = *(const uint4*)(H + (size_t)r0 * 256 + B);
      *(uint4*)(lb + addr) = v;
    }
  }
  __syncthreads();

  const int cbase = wave * 32;
  s16x8 Af[2][4];
#pragma unroll
  for (int m = 0; m < 2; ++m)
#pragma unroll
    for (int ks = 0; ks < 4; ++ks)
      Af[m][ks] = *(const s16x8*)&Wt[(cbase + m * 16 + l15) * DD + ks * 32 + lk16 * 8];

  s16x8 Bf[2][4];
#pragma unroll
  for (int n = 0; n < 2; ++n) {
    const int row = n * 16 + l15;
#pragma unroll
    for (int ks = 0; ks < 4; ++ks) {
      const int B = row * 256 + ks * 64 + lk16 * 16;
      Bf[n][ks] = *(const s16x8*)(lb + (B ^ ((row & 7) << 4)));
    }
  }

  f32x4 acc[2][2];
#pragma unroll
  for (int m = 0; m < 2; ++m)
#pragma unroll
    for (int n = 0; n < 2; ++n) acc[m][n] = (f32x4){0.f, 0.f, 0.f, 0.f};

#pragma unroll
  for (int ks = 0; ks < 4; ++ks)
#pragma unroll
    for (int m = 0; m < 2; ++m)
#pragma unroll
      for (int n = 0; n < 2; ++n)
        acc[m][n] = __builtin_amdgcn_mfma_f32_16x16x32_bf16(Af[m][ks], Bf[n][ks],
                                                            acc[m][n], 0, 0, 0);

  // ---- encode fp8, stage 32x128B tile through LDS, linear stores ----
  __syncthreads();
#pragma unroll
  for (int m = 0; m < 2; ++m)
#pragma unroll
    for (int n = 0; n < 2; ++n) {
      const int row = n * 16 + l15;
      const int colb = cbase + m * 16 + 4 * lk16;   // byte == col (fp8)
      const int B = row * 128 + colb;
      unsigned int pv = f2fp8(acc[m][n][0]) | (f2fp8(acc[m][n][1]) << 8)
                      | (f2fp8(acc[m][n][2]) << 16) | (f2fp8(acc[m][n][3]) << 24);
      *(unsigned int*)(lb + (B ^ ((row & 7) << 4))) = pv;
    }
  __syncthreads();
  {
    const int B = threadIdx.x * 16;     // 256 thr x 16B = 4KB tile
    const int row = B >> 7;
    uint4 v = *(const uint4*)(lb + (B ^ ((row & 7) << 4)));
    *(uint4*)(Sout + (size_t)r0 * 128 + B) = v;
  }
}

// ---- aggregation over custom fp8 S, pure-VALU decode (no LDS in hot loop) ----
// wave = 4 quads x 16 lanes; quad q owns edge slot q; lane t covers cols t*8..t*8+7
// (8 fp8 = uint2 = 8B gather; 16 lanes x 8B = full 128B row = 1 cache line).
// w is pre-scaled by 2^120 so decode is two masked shifts + or.
__device__ __forceinline__ void fma8v(float* acc, float w, uint2 u) {
#pragma unroll
  for (int h = 0; h < 2; ++h) {
    const unsigned int v = h ? u.y : u.x;
#pragma unroll
    for (int j = 0; j < 4; ++j) {
      const unsigned int c = (v >> (8 * j)) & 255u;
      const float dec = __uint_as_float(((c & 0x80u) << 24) | ((c & 0x7Fu) << 20));
      acc[h * 4 + j] = fmaf(w, dec, acc[h * 4 + j]);
    }
  }
}

__global__ __launch_bounds__(256) void k_agg(const unsigned char* __restrict__ S,
                                             const int2* __restrict__ csr,
                                             const int* __restrict__ offs,
                                             const float* __restrict__ bias,
                                             unsigned short* __restrict__ Xout,  // may be null
                                             unsigned int* __restrict__ omax,
                                             int do_relu) {
  __shared__ unsigned int cmax[DD];
  for (int i = threadIdx.x; i < DD; i += 256) cmax[i] = 0u;
  __syncthreads();
  const int lane = threadIdx.x & 63;
  const int wave = threadIdx.x >> 6;
  const int q = lane >> 4;
  const int t = lane & 15;
  const int gwave = blockIdx.x * 4 + wave;
  const int nwaves = gridDim.x * 4;
  const unsigned char* Sc = S + t * 8;
  const float SCALE = 0x1p120f;

  float bcol[8];
  {
    float4 b0 = *(const float4*)&bias[t * 8];
    float4 b1 = *(const float4*)&bias[t * 8 + 4];
    bcol[0] = b0.x; bcol[1] = b0.y; bcol[2] = b0.z; bcol[3] = b0.w;
    bcol[4] = b1.x; bcol[5] = b1.y; bcol[6] = b1.z; bcol[7] = b1.w;
  }
  float mx[8];
#pragma unroll
  for (int j = 0; j < 8; ++j) mx[j] = -INFINITY;

  for (int d = gwave; d < NN; d += nwaves) {
    const int e0 = offs[d], e1 = offs[d + 1];
    const int nedge = e1 - e0;
    float acc[8] = {0.f, 0.f, 0.f, 0.f, 0.f, 0.f, 0.f, 0.f};
    int e = e0 + q;
    int done = 0;
    for (; done + 16 <= nedge; done += 16, e += 16) {
      int2 a0 = csr[e];      int2 a1 = csr[e + 4];
      int2 a2 = csr[e + 8];  int2 a3 = csr[e + 12];
      uint2 u0 = *(const uint2*)&Sc[(size_t)a0.x * DD];
      uint2 u1 = *(const uint2*)&Sc[(size_t)a1.x * DD];
      uint2 u2 = *(const uint2*)&Sc[(size_t)a2.x * DD];
      uint2 u3 = *(const uint2*)&Sc[(size_t)a3.x * DD];
      fma8v(acc, __int_as_float(a0.y) * SCALE, u0);
      fma8v(acc, __int_as_float(a1.y) * SCALE, u1);
      fma8v(acc, __int_as_float(a2.y) * SCALE, u2);
      fma8v(acc, __int_as_float(a3.y) * SCALE, u3);
    }
    if (done + 8 <= nedge) {
      int2 a0 = csr[e];      int2 a1 = csr[e + 4];
      uint2 u0 = *(const uint2*)&Sc[(size_t)a0.x * DD];
      uint2 u1 = *(const uint2*)&Sc[(size_t)a1.x * DD];
      fma8v(acc, __int_as_float(a0.y) * SCALE, u0);
      fma8v(acc, __int_as_float(a1.y) * SCALE, u1);
      done += 8; e += 8;
    }
    while (__any(e < e1)) {
      if (e < e1) {
        int2 c = csr[e];
        uint2 u = *(const uint2*)&Sc[(size_t)c.x * DD];
        fma8v(acc, __int_as_float(c.y) * SCALE, u);
      }
      e += 4;
    }
    // cross-quad butterfly reduce + finalize
#pragma unroll
    for (int j = 0; j < 8; ++j) {
      acc[j] += __shfl_xor(acc[j], 16, 64);
      acc[j] += __shfl_xor(acc[j], 32, 64);
      acc[j] += bcol[j];
      if (do_relu) acc[j] = fmaxf(acc[j], 0.f);
      mx[j] = fmaxf(mx[j], acc[j]);
    }
    if (Xout && q == 0) {
      uint4 xv;
      xv.x = (uint)f2bf(acc[0]) | ((uint)f2bf(acc[1]) << 16);
      xv.y = (uint)f2bf(acc[2]) | ((uint)f2bf(acc[3]) << 16);
      xv.z = (uint)f2bf(acc[4]) | ((uint)f2bf(acc[5]) << 16);
      xv.w = (uint)f2bf(acc[6]) | ((uint)f2bf(acc[7]) << 16);
      *(uint4*)&Xout[(size_t)d * DD + t * 8] = xv;
    }
  }
  if (q == 0) {
#pragma unroll
    for (int j = 0; j < 8; ++j) atomicMax(&cmax[t * 8 + j], fkey(mx[j]));
  }
  __syncthreads();
  for (int i = threadIdx.x; i < DD; i += 256) atomicMax(&omax[i], cmax[i]);
}

// ---- head ----
__global__ void k_head(const unsigned int* __restrict__ omax,
                       const float* __restrict__ linW,
                       const float* __restrict__ linb,
                       float* __restrict__ out) {
  __shared__ float o[3 * DD];
  __shared__ float logits[NCLS];
  int t = threadIdx.x;  // block = 384
  if (t < 3 * DD) o[t] = funkey(omax[t]);
  __syncthreads();
  if (t < NCLS) {
    float acc = linb[t];
    for (int j = 0; j < 3 * DD; ++j) acc = fmaf(linW[t * 3 * DD + j], o[j], acc);
    logits[t] = acc;
  }
  __syncthreads();
  if (t == 0) {
    float m = -INFINITY;
    for (int c = 0; c < NCLS; ++c) m = fmaxf(m, logits[c]);
    float s = 0.f;
    for (int c = 0; c < NCLS; ++c) s += expf(logits[c] - m);
    float ls = logf(s);
    for (int c = 0; c < NCLS; ++c) out[c] = logits[c] - m - ls;
  }
}

extern "C" void kernel_launch(void* const* d_in, const int* in_sizes, int n_in,
                              void* d_out, int out_size, void* d_ws, size_t ws_size,
                              hipStream_t stream) {
  const float* x    = (const float*)d_in[0];
  const int*   esrc = (const int*)d_in[1];
  const int*   edst = (const int*)d_in[2];
  const float* ew   = (const float*)d_in[3];
  const float* W1   = (const float*)d_in[4];
  const float* b1   = (const float*)d_in[5];
  const float* W2   = (const float*)d_in[6];
  const float* b2   = (const float*)d_in[7];
  const float* W3   = (const float*)d_in[8];
  const float* b3   = (const float*)d_in[9];
  const float* linW = (const float*)d_in[10];
  const float* linb = (const float*)d_in[11];
  float* out = (float*)d_out;

  size_t off = 0;
  auto alloc = [&](size_t bytes) {
    void* p = (char*)d_ws + off;
    off += (bytes + 255) & ~(size_t)255;
    return p;
  };
  unsigned short* X1   = (unsigned short*)alloc((size_t)NPAD * DD * 2);
  unsigned short* X2   = (unsigned short*)alloc((size_t)NPAD * DD * 2);
  unsigned char*  S    = (unsigned char*)alloc((size_t)NPAD * DD);     // fp8
  unsigned short* WT1  = (unsigned short*)alloc((size_t)DD * DD * 2);
  unsigned short* WT2  = (unsigned short*)alloc((size_t)DD * DD * 2);
  unsigned short* WT3  = (unsigned short*)alloc((size_t)DD * DD * 2);
  int*          offs   = (int*)alloc((NN + 2) * 4);
  int*          cursor = (int*)alloc(NN * 4);
  int2*         csr    = (int2*)alloc((size_t)NE * 8);
  unsigned int* omax   = (unsigned int*)alloc(3 * DD * 4);
  int*          bsum   = (int*)alloc(NTILES * 4);
  (void)ws_size; (void)n_in; (void)in_sizes; (void)out_size;

  // CSR build (shared by all 3 layers)
  hipMemsetAsync(offs, 0, (NN + 2) * 4, stream);
  k_count<<<(NE + 255) / 256, 256, 0, stream>>>(edst, offs);
  k_scan_partial<<<NTILES, SCAN_BLOCK, 0, stream>>>(offs, bsum);
  k_scan_bsum<<<1, 64, 0, stream>>>(bsum);
  k_scan_final<<<NTILES, SCAN_BLOCK, 0, stream>>>(offs, bsum, cursor);
  k_fill<<<(NE + 255) / 256, 256, 0, stream>>>(esrc, edst, ew, cursor, csr);

  k_cvtW<<<(DD * DD + 255) / 256, 256, 0, stream>>>(W1, W2, W3, WT1, WT2, WT3, omax);

  const int mm_grid = NPAD / 32;  // 1564
  // layer 1 (fp32 x read + convert fused into GEMM staging)
  k_mm<1><<<mm_grid, 256, 0, stream>>>(x, WT1, S);
  k_agg<<<2048, 256, 0, stream>>>(S, csr, offs, b1, X1, omax, 1);
  // layer 2
  k_mm<0><<<mm_grid, 256, 0, stream>>>(X1, WT2, S);
  k_agg<<<2048, 256, 0, stream>>>(S, csr, offs, b2, X2, omax + DD, 1);
  // layer 3 (no X store, no relu)
  k_mm<0><<<mm_grid, 256, 0, stream>>>(X2, WT3, S);
  k_agg<<<2048, 256, 0, stream>>>(S, csr, offs, b3, nullptr, omax + 2 * DD, 0);

  k_head<<<1, 384, 0, stream>>>(omax, linW, linb, out);
}

// Round 10
// 425.646 us; speedup vs baseline: 1.0447x; 1.0447x over previous
//
#include <hip/hip_runtime.h>
#include <hip/hip_bf16.h>
#include <math.h>

#define NN 50000
#define NPAD 50048            // 1564 chunks of 32 rows
#define NE 800000
#define DD 128
#define NCLS 10
#define SCAN_BLOCK 1024
#define NTILES ((NN + 1 + SCAN_BLOCK - 1) / SCAN_BLOCK)  // 49

typedef short s16x8 __attribute__((ext_vector_type(8)));
typedef float f32x4 __attribute__((ext_vector_type(4)));

__device__ __forceinline__ unsigned short f2bf(float x) {
  __hip_bfloat16 h = __float2bfloat16(x);
  return __builtin_bit_cast(unsigned short, h);
}

// ---- custom fp8: s|eeee|mmm, bias 7, no denormals (flush |v|<2^-6), sat 480.
// decode = as_float(((c&0x80)<<24)|((c&0x7F)<<20)) * 2^120  (scale folded into w).
__device__ __forceinline__ unsigned int f2fp8(float x) {
  unsigned int b = __float_as_uint(x);
  unsigned int s = (b >> 24) & 0x80u;
  int e = (int)((b >> 23) & 255u) - 120;   // target exp field
  unsigned int m23 = b & 0x7FFFFFu;
  if (e >= 16) return s | 0x7F;            // saturate to 480
  if (e <= 0) return s;                    // flush to zero
  unsigned int m = m23 >> 20;              // 3 mantissa bits
  unsigned int rem = m23 & 0xFFFFFu;
  if (rem > 0x80000u || (rem == 0x80000u && (m & 1u))) {
    ++m;
    if (m == 8u) { m = 0; ++e; if (e >= 16) return s | 0x7F; }
  }
  return s | ((unsigned int)e << 3) | m;
}

// ---- monotonic float<->uint key for atomic max over floats ----
__device__ __forceinline__ unsigned int fkey(float f) {
  unsigned int u = __float_as_uint(f);
  return u ^ ((u & 0x80000000u) ? 0xFFFFFFFFu : 0x80000000u);
}
__device__ __forceinline__ float funkey(unsigned int k) {
  unsigned int u = (k & 0x80000000u) ? (k ^ 0x80000000u) : ~k;
  return __uint_as_float(u);
}

// ---- CSR build ----
__global__ void k_count(const int* __restrict__ edst, int* __restrict__ offs) {
  int e = blockIdx.x * blockDim.x + threadIdx.x;
  if (e < NE) atomicAdd(&offs[edst[e] + 1], 1);
}

__global__ void k_scan_partial(const int* __restrict__ offs, int* __restrict__ bsum) {
  __shared__ int red[SCAN_BLOCK];
  int i = blockIdx.x * SCAN_BLOCK + threadIdx.x;
  red[threadIdx.x] = (i < NN + 1) ? offs[i] : 0;
  __syncthreads();
  for (int off = SCAN_BLOCK / 2; off > 0; off >>= 1) {
    if ((int)threadIdx.x < off) red[threadIdx.x] += red[threadIdx.x + off];
    __syncthreads();
  }
  if (threadIdx.x == 0) bsum[blockIdx.x] = red[0];
}

__global__ void k_scan_bsum(int* __restrict__ bsum) {
  if (threadIdx.x == 0) {
    int run = 0;
    for (int i = 0; i < NTILES; ++i) { int v = bsum[i]; bsum[i] = run; run += v; }
  }
}

__global__ void k_scan_final(int* __restrict__ offs, const int* __restrict__ bsum,
                             int* __restrict__ cursor) {
  __shared__ int tmp[SCAN_BLOCK];
  int i = blockIdx.x * SCAN_BLOCK + threadIdx.x;
  int v = (i < NN + 1) ? offs[i] : 0;
  tmp[threadIdx.x] = v;
  __syncthreads();
  for (int off = 1; off < SCAN_BLOCK; off <<= 1) {
    int t = ((int)threadIdx.x >= off) ? tmp[threadIdx.x - off] : 0;
    __syncthreads();
    tmp[threadIdx.x] += t;
    __syncthreads();
  }
  int incl = tmp[threadIdx.x] + bsum[blockIdx.x];
  if (i < NN + 1) {
    offs[i] = incl;
    if (i < NN) cursor[i] = incl;
  }
}

// csr entry = 4B: (w16 << 16) | src16.  w16 = round(w * 65535), src < 65536.
__global__ void k_fill(const int* __restrict__ esrc, const int* __restrict__ edst,
                       const float* __restrict__ ew, int* __restrict__ cursor,
                       unsigned int* __restrict__ csr) {
  int e = blockIdx.x * blockDim.x + threadIdx.x;
  if (e < NE) {
    int d = edst[e];
    int p = atomicAdd(&cursor[d], 1);
    unsigned int w16 = (unsigned int)(ew[e] * 65535.0f + 0.5f);
    csr[p] = (w16 << 16) | (unsigned int)esrc[e];
  }
}

// ---- convert W1..3 -> transposed bf16 WT[c][k]; also zero omax ----
__global__ __launch_bounds__(256) void k_cvtW(const float* __restrict__ W1,
    const float* __restrict__ W2, const float* __restrict__ W3,
    unsigned short* __restrict__ WT1, unsigned short* __restrict__ WT2,
    unsigned short* __restrict__ WT3, unsigned int* __restrict__ omax) {
  int i = blockIdx.x * 256 + threadIdx.x;
  if (i < 3 * DD) omax[i] = 0u;
  if (i < DD * DD) {
    int k = i >> 7, c = i & 127;
    WT1[c * DD + k] = f2bf(W1[i]);
    WT2[c * DD + k] = f2bf(W2[i]);
    WT3[c * DD + k] = f2bf(W3[i]);
  }
}

// ---- MFMA GEMM, persistent blocks: S[r][c] = fp8(sum_k H[r][k] W[k][c]) ----
// grid = 512, block = 256 (4 waves). W staged once per block in LDS (swizzled),
// W-fragments hoisted to registers; 3-4 tiles of 32 rows per block.
template <int F32IN>
__global__ __launch_bounds__(256) void k_mm(const void* __restrict__ Hv,
                                            const unsigned short* __restrict__ Wt,
                                            unsigned char* __restrict__ Sout) {
  __shared__ unsigned short Wl[DD * DD];   // 32 KB, swizzled
  __shared__ unsigned short Hl[32 * DD];   // 8 KB, swizzled; reused for out staging
  char* wb = (char*)Wl;
  char* lb = (char*)Hl;
  const int wave = threadIdx.x >> 6, lane = threadIdx.x & 63;
  const int l15 = lane & 15, lk16 = (lane >> 4);

  // stage W (Wt[c][k] bf16, 256B rows) into LDS, coalesced, swizzled
#pragma unroll
  for (int j = 0; j < 8; ++j) {
    const int idx = threadIdx.x + j * 256;   // 2048 granules of 16B
    const int B = idx * 16;
    const int row = B >> 8;
    *(uint4*)(wb + (B ^ ((row & 7) << 4))) = *(const uint4*)((const char*)Wt + B);
  }
  __syncthreads();

  // hoist W fragments (invariant across tiles)
  const int cbase = wave * 32;
  s16x8 Af[2][4];
#pragma unroll
  for (int m = 0; m < 2; ++m)
#pragma unroll
    for (int ks = 0; ks < 4; ++ks) {
      const int row = cbase + m * 16 + l15;
      const int B = row * 256 + ks * 64 + lk16 * 16;
      Af[m][ks] = *(const s16x8*)(wb + (B ^ ((row & 7) << 4)));
    }

  for (int t = blockIdx.x; t < NPAD / 32; t += gridDim.x) {
    const int r0 = t * 32;
    __syncthreads();   // previous tile's store phase done; Hl free

    // stage 32x128 bf16 tile into LDS, coalesced, swizzled
#pragma unroll
    for (int j = 0; j < 2; ++j) {
      const int idx = threadIdx.x + j * 256;     // 512 granules of 16B
      const int B = idx * 16;
      const int row = B >> 8;
      const int addr = B ^ ((row & 7) << 4);
      if (F32IN) {
        const float* H = (const float*)Hv;
        const int r = r0 + row;
        float4 a = make_float4(0.f, 0.f, 0.f, 0.f), b = a;
        if (r < NN) {
          const float* src = H + (size_t)r * DD + ((B & 255) >> 1);
          a = *(const float4*)src;
          b = *(const float4*)(src + 4);
        }
        uint4 pv;
        pv.x = (uint)f2bf(a.x) | ((uint)f2bf(a.y) << 16);
        pv.y = (uint)f2bf(a.z) | ((uint)f2bf(a.w) << 16);
        pv.z = (uint)f2bf(b.x) | ((uint)f2bf(b.y) << 16);
        pv.w = (uint)f2bf(b.z) | ((uint)f2bf(b.w) << 16);
        *(uint4*)(lb + addr) = pv;
      } else {
        const char* H = (const char*)Hv;
        uint4 v = *(const uint4*)(H + (size_t)r0 * 256 + B);
        *(uint4*)(lb + addr) = v;
      }
    }
    __syncthreads();

    s16x8 Bf[2][4];
#pragma unroll
    for (int n = 0; n < 2; ++n) {
      const int row = n * 16 + l15;
#pragma unroll
      for (int ks = 0; ks < 4; ++ks) {
        const int B = row * 256 + ks * 64 + lk16 * 16;
        Bf[n][ks] = *(const s16x8*)(lb + (B ^ ((row & 7) << 4)));
      }
    }

    f32x4 acc[2][2];
#pragma unroll
    for (int m = 0; m < 2; ++m)
#pragma unroll
      for (int n = 0; n < 2; ++n) acc[m][n] = (f32x4){0.f, 0.f, 0.f, 0.f};

#pragma unroll
    for (int ks = 0; ks < 4; ++ks)
#pragma unroll
      for (int m = 0; m < 2; ++m)
#pragma unroll
        for (int n = 0; n < 2; ++n)
          acc[m][n] = __builtin_amdgcn_mfma_f32_16x16x32_bf16(Af[m][ks], Bf[n][ks],
                                                              acc[m][n], 0, 0, 0);

    __syncthreads();
    // encode fp8, stage 32x128B tile through LDS, linear stores
#pragma unroll
    for (int m = 0; m < 2; ++m)
#pragma unroll
      for (int n = 0; n < 2; ++n) {
        const int row = n * 16 + l15;
        const int colb = cbase + m * 16 + 4 * lk16;   // byte == col (fp8)
        const int B = row * 128 + colb;
        unsigned int pv = f2fp8(acc[m][n][0]) | (f2fp8(acc[m][n][1]) << 8)
                        | (f2fp8(acc[m][n][2]) << 16) | (f2fp8(acc[m][n][3]) << 24);
        *(unsigned int*)(lb + (B ^ ((row & 7) << 4))) = pv;
      }
    __syncthreads();
    {
      const int B = threadIdx.x * 16;     // 256 thr x 16B = 4KB tile
      const int row = B >> 7;
      uint4 v = *(const uint4*)(lb + (B ^ ((row & 7) << 4)));
      *(uint4*)(Sout + (size_t)r0 * 128 + B) = v;
    }
  }
}

// ---- aggregation over custom fp8 S, pure-VALU decode, 4B csr entries ----
// wave = 4 quads x 16 lanes; quad q owns edge slot q; lane t covers cols t*8..t*8+7.
__device__ __forceinline__ void fma8v(float* acc, float w, uint2 u) {
#pragma unroll
  for (int h = 0; h < 2; ++h) {
    const unsigned int v = h ? u.y : u.x;
#pragma unroll
    for (int j = 0; j < 4; ++j) {
      const unsigned int c = (v >> (8 * j)) & 255u;
      const float dec = __uint_as_float(((c & 0x80u) << 24) | ((c & 0x7Fu) << 20));
      acc[h * 4 + j] = fmaf(w, dec, acc[h * 4 + j]);
    }
  }
}

__global__ __launch_bounds__(256) void k_agg(const unsigned char* __restrict__ S,
                                             const unsigned int* __restrict__ csr,
                                             const int* __restrict__ offs,
                                             const float* __restrict__ bias,
                                             unsigned short* __restrict__ Xout,  // may be null
                                             unsigned int* __restrict__ omax,
                                             int do_relu) {
  __shared__ unsigned int cmax[DD];
  for (int i = threadIdx.x; i < DD; i += 256) cmax[i] = 0u;
  __syncthreads();
  const int lane = threadIdx.x & 63;
  const int wave = threadIdx.x >> 6;
  const int q = lane >> 4;
  const int t = lane & 15;
  const int gwave = blockIdx.x * 4 + wave;
  const int nwaves = gridDim.x * 4;
  const unsigned char* Sc = S + t * 8;
  const float WSC = 0x1p120f / 65535.0f;   // w16 decode * fp8 scale

  float bcol[8];
  {
    float4 b0 = *(const float4*)&bias[t * 8];
    float4 b1 = *(const float4*)&bias[t * 8 + 4];
    bcol[0] = b0.x; bcol[1] = b0.y; bcol[2] = b0.z; bcol[3] = b0.w;
    bcol[4] = b1.x; bcol[5] = b1.y; bcol[6] = b1.z; bcol[7] = b1.w;
  }
  float mx[8];
#pragma unroll
  for (int j = 0; j < 8; ++j) mx[j] = -INFINITY;

  for (int d = gwave; d < NN; d += nwaves) {
    const int e0 = offs[d], e1 = offs[d + 1];
    const int nedge = e1 - e0;
    float acc[8] = {0.f, 0.f, 0.f, 0.f, 0.f, 0.f, 0.f, 0.f};
    int e = e0 + q;
    int done = 0;
    for (; done + 16 <= nedge; done += 16, e += 16) {
      unsigned int a0 = csr[e];      unsigned int a1 = csr[e + 4];
      unsigned int a2 = csr[e + 8];  unsigned int a3 = csr[e + 12];
      uint2 u0 = *(const uint2*)&Sc[(size_t)(a0 & 0xFFFFu) * DD];
      uint2 u1 = *(const uint2*)&Sc[(size_t)(a1 & 0xFFFFu) * DD];
      uint2 u2 = *(const uint2*)&Sc[(size_t)(a2 & 0xFFFFu) * DD];
      uint2 u3 = *(const uint2*)&Sc[(size_t)(a3 & 0xFFFFu) * DD];
      fma8v(acc, (float)(a0 >> 16) * WSC, u0);
      fma8v(acc, (float)(a1 >> 16) * WSC, u1);
      fma8v(acc, (float)(a2 >> 16) * WSC, u2);
      fma8v(acc, (float)(a3 >> 16) * WSC, u3);
    }
    if (done + 8 <= nedge) {
      unsigned int a0 = csr[e];      unsigned int a1 = csr[e + 4];
      uint2 u0 = *(const uint2*)&Sc[(size_t)(a0 & 0xFFFFu) * DD];
      uint2 u1 = *(const uint2*)&Sc[(size_t)(a1 & 0xFFFFu) * DD];
      fma8v(acc, (float)(a0 >> 16) * WSC, u0);
      fma8v(acc, (float)(a1 >> 16) * WSC, u1);
      done += 8; e += 8;
    }
    while (__any(e < e1)) {
      if (e < e1) {
        unsigned int c = csr[e];
        uint2 u = *(const uint2*)&Sc[(size_t)(c & 0xFFFFu) * DD];
        fma8v(acc, (float)(c >> 16) * WSC, u);
      }
      e += 4;
    }
    // cross-quad butterfly reduce + finalize
#pragma unroll
    for (int j = 0; j < 8; ++j) {
      acc[j] += __shfl_xor(acc[j], 16, 64);
      acc[j] += __shfl_xor(acc[j], 32, 64);
      acc[j] += bcol[j];
      if (do_relu) acc[j] = fmaxf(acc[j], 0.f);
      mx[j] = fmaxf(mx[j], acc[j]);
    }
    if (Xout && q == 0) {
      uint4 xv;
      xv.x = (uint)f2bf(acc[0]) | ((uint)f2bf(acc[1]) << 16);
      xv.y = (uint)f2bf(acc[2]) | ((uint)f2bf(acc[3]) << 16);
      xv.z = (uint)f2bf(acc[4]) | ((uint)f2bf(acc[5]) << 16);
      xv.w = (uint)f2bf(acc[6]) | ((uint)f2bf(acc[7]) << 16);
      *(uint4*)&Xout[(size_t)d * DD + t * 8] = xv;
    }
  }
  if (q == 0) {
#pragma unroll
    for (int j = 0; j < 8; ++j) atomicMax(&cmax[t * 8 + j], fkey(mx[j]));
  }
  __syncthreads();
  for (int i = threadIdx.x; i < DD; i += 256) atomicMax(&omax[i], cmax[i]);
}

// ---- head ----
__global__ void k_head(const unsigned int* __restrict__ omax,
                       const float* __restrict__ linW,
                       const float* __restrict__ linb,
                       float* __restrict__ out) {
  __shared__ float o[3 * DD];
  __shared__ float logits[NCLS];
  int t = threadIdx.x;  // block = 384
  if (t < 3 * DD) o[t] = funkey(omax[t]);
  __syncthreads();
  if (t < NCLS) {
    float acc = linb[t];
    for (int j = 0; j < 3 * DD; ++j) acc = fmaf(linW[t * 3 * DD + j], o[j], acc);
    logits[t] = acc;
  }
  __syncthreads();
  if (t == 0) {
    float m = -INFINITY;
    for (int c = 0; c < NCLS; ++c) m = fmaxf(m, logits[c]);
    float s = 0.f;
    for (int c = 0; c < NCLS; ++c) s += expf(logits[c] - m);
    float ls = logf(s);
    for (int c = 0; c < NCLS; ++c) out[c] = logits[c] - m - ls;
  }
}

extern "C" void kernel_launch(void* const* d_in, const int* in_sizes, int n_in,
                              void* d_out, int out_size, void* d_ws, size_t ws_size,
                              hipStream_t stream) {
  const float* x    = (const float*)d_in[0];
  const int*   esrc = (const int*)d_in[1];
  const int*   edst = (const int*)d_in[2];
  const float* ew   = (const float*)d_in[3];
  const float* W1   = (const float*)d_in[4];
  const float* b1   = (const float*)d_in[5];
  const float* W2   = (const float*)d_in[6];
  const float* b2   = (const float*)d_in[7];
  const float* W3   = (const float*)d_in[8];
  const float* b3   = (const float*)d_in[9];
  const float* linW = (const float*)d_in[10];
  const float* linb = (const float*)d_in[11];
  float* out = (float*)d_out;

  size_t off = 0;
  auto alloc = [&](size_t bytes) {
    void* p = (char*)d_ws + off;
    off += (bytes + 255) & ~(size_t)255;
    return p;
  };
  unsigned short* X1   = (unsigned short*)alloc((size_t)NPAD * DD * 2);
  unsigned short* X2   = (unsigned short*)alloc((size_t)NPAD * DD * 2);
  unsigned char*  S    = (unsigned char*)alloc((size_t)NPAD * DD);     // fp8
  unsigned short* WT1  = (unsigned short*)alloc((size_t)DD * DD * 2);
  unsigned short* WT2  = (unsigned short*)alloc((size_t)DD * DD * 2);
  unsigned short* WT3  = (unsigned short*)alloc((size_t)DD * DD * 2);
  int*          offs   = (int*)alloc((NN + 2) * 4);
  int*          cursor = (int*)alloc(NN * 4);
  unsigned int* csr    = (unsigned int*)alloc((size_t)NE * 4);         // 4B entries
  unsigned int* omax   = (unsigned int*)alloc(3 * DD * 4);
  int*          bsum   = (int*)alloc(NTILES * 4);
  (void)ws_size; (void)n_in; (void)in_sizes; (void)out_size;

  // CSR build (shared by all 3 layers)
  hipMemsetAsync(offs, 0, (NN + 2) * 4, stream);
  k_count<<<(NE + 255) / 256, 256, 0, stream>>>(edst, offs);
  k_scan_partial<<<NTILES, SCAN_BLOCK, 0, stream>>>(offs, bsum);
  k_scan_bsum<<<1, 64, 0, stream>>>(bsum);
  k_scan_final<<<NTILES, SCAN_BLOCK, 0, stream>>>(offs, bsum, cursor);
  k_fill<<<(NE + 255) / 256, 256, 0, stream>>>(esrc, edst, ew, cursor, csr);

  k_cvtW<<<(DD * DD + 255) / 256, 256, 0, stream>>>(W1, W2, W3, WT1, WT2, WT3, omax);

  const int mm_grid = 512;   // persistent blocks, 3-4 tiles each
  // layer 1 (fp32 x read + convert fused into GEMM staging)
  k_mm<1><<<mm_grid, 256, 0, stream>>>(x, WT1, S);
  k_agg<<<2048, 256, 0, stream>>>(S, csr, offs, b1, X1, omax, 1);
  // layer 2
  k_mm<0><<<mm_grid, 256, 0, stream>>>(X1, WT2, S);
  k_agg<<<2048, 256, 0, stream>>>(S, csr, offs, b2, X2, omax + DD, 1);
  // layer 3 (no X store, no relu)
  k_mm<0><<<mm_grid, 256, 0, stream>>>(X2, WT3, S);
  k_agg<<<2048, 256, 0, stream>>>(S, csr, offs, b3, nullptr, omax + 2 * DD, 0);

  k_head<<<1, 384, 0, stream>>>(omax, linW, linb, out);
}